// Round 1
// baseline (1577.029 us; speedup 1.0000x reference)
//
#include <hip/hip_runtime.h>
#include <math.h>

// ---------------- transform: T[R x 128] = X[R x 768] @ M[768 x 128] ----------------
__global__ __launch_bounds__(256) void transform_kernel(
    const float* __restrict__ X, const float* __restrict__ Mw,
    float* __restrict__ T)
{
  __shared__ float xs[32][33];
  const int tid = threadIdx.x;
  const int col = tid & 127;
  const int rh  = tid >> 7;            // 0..1
  const int rbase = blockIdx.x * 32;
  float acc[16];
#pragma unroll
  for (int r = 0; r < 16; ++r) acc[r] = 0.f;
  const int lr = tid >> 3;             // 0..31
  const int lk = (tid & 7) * 4;        // 0,4,...,28
  for (int kc = 0; kc < 768; kc += 32) {
    const float4 v = *reinterpret_cast<const float4*>(&X[(size_t)(rbase + lr) * 768 + kc + lk]);
    xs[lr][lk + 0] = v.x; xs[lr][lk + 1] = v.y; xs[lr][lk + 2] = v.z; xs[lr][lk + 3] = v.w;
    __syncthreads();
#pragma unroll
    for (int kk = 0; kk < 32; ++kk) {
      const float mv = Mw[(size_t)(kc + kk) * 128 + col];
#pragma unroll
      for (int r = 0; r < 16; ++r)
        acc[r] = fmaf(xs[rh * 16 + r][kk], mv, acc[r]);
    }
    __syncthreads();
  }
#pragma unroll
  for (int r = 0; r < 16; ++r)
    T[(size_t)(rbase + rh * 16 + r) * 128 + col] = acc[r];
}

// ---------------- row squared norms ----------------
__global__ __launch_bounds__(256) void rownorm_kernel(
    const float* __restrict__ X, float* __restrict__ nrm, int R)
{
  const int wv = threadIdx.x >> 6, ln = threadIdx.x & 63;
  const int row = blockIdx.x * 4 + wv;
  if (row >= R) return;
  const float2 v = reinterpret_cast<const float2*>(X + (size_t)row * 128)[ln];
  float s = fmaf(v.x, v.x, v.y * v.y);
#pragma unroll
  for (int off = 32; off; off >>= 1) s += __shfl_xor(s, off);
  if (ln == 0) nrm[row] = s;
}

// ---------------- cost matrix: C[i][j] = 0.5*max(nx+ny-2*x.y, 0); optional transpose ----------------
__global__ __launch_bounds__(256) void cost_kernel(
    const float* __restrict__ X, const float* __restrict__ Y,
    const float* __restrict__ nx, const float* __restrict__ ny,
    float* __restrict__ C, float* __restrict__ CT,
    int N, int Mc)
{
  __shared__ __align__(16) float xs[64][68];
  __shared__ __align__(16) float ys[64][68];
  const int tid = threadIdx.x;
  const int i0 = blockIdx.x * 64;
  const int j0 = blockIdx.y * 64;
  const int tx = tid & 15;   // cols: tx + 16*c
  const int ty = tid >> 4;   // rows: ty*4 + r
  float acc[4][4];
#pragma unroll
  for (int r = 0; r < 4; ++r)
#pragma unroll
    for (int c = 0; c < 4; ++c) acc[r][c] = 0.f;

  for (int kc = 0; kc < 128; kc += 64) {
#pragma unroll
    for (int t = 0; t < 4; ++t) {
      const int fi = tid + t * 256;
      const int row = fi >> 4;
      const int k4 = (fi & 15) * 4;
      *reinterpret_cast<float4*>(&xs[row][k4]) =
          *reinterpret_cast<const float4*>(&X[(size_t)(i0 + row) * 128 + kc + k4]);
      *reinterpret_cast<float4*>(&ys[row][k4]) =
          *reinterpret_cast<const float4*>(&Y[(size_t)(j0 + row) * 128 + kc + k4]);
    }
    __syncthreads();
#pragma unroll
    for (int k = 0; k < 64; k += 4) {
      float4 xv[4], yv[4];
#pragma unroll
      for (int r = 0; r < 4; ++r)
        xv[r] = *reinterpret_cast<const float4*>(&xs[ty * 4 + r][k]);
#pragma unroll
      for (int c = 0; c < 4; ++c)
        yv[c] = *reinterpret_cast<const float4*>(&ys[tx + 16 * c][k]);
#pragma unroll
      for (int r = 0; r < 4; ++r)
#pragma unroll
        for (int c = 0; c < 4; ++c) {
          acc[r][c] = fmaf(xv[r].x, yv[c].x, acc[r][c]);
          acc[r][c] = fmaf(xv[r].y, yv[c].y, acc[r][c]);
          acc[r][c] = fmaf(xv[r].z, yv[c].z, acc[r][c]);
          acc[r][c] = fmaf(xv[r].w, yv[c].w, acc[r][c]);
        }
    }
    __syncthreads();
  }
  float vnx[4], vny[4];
#pragma unroll
  for (int r = 0; r < 4; ++r) vnx[r] = nx[i0 + ty * 4 + r];
#pragma unroll
  for (int c = 0; c < 4; ++c) vny[c] = ny[j0 + tx + 16 * c];
  float cv[4][4];
#pragma unroll
  for (int r = 0; r < 4; ++r)
#pragma unroll
    for (int c = 0; c < 4; ++c) {
      const float sq = vnx[r] + vny[c] - 2.f * acc[r][c];
      cv[r][c] = 0.5f * fmaxf(sq, 0.f);
      C[(size_t)(i0 + ty * 4 + r) * Mc + (j0 + tx + 16 * c)] = cv[r][c];
    }
  if (CT != nullptr) {
    float* tt = &xs[0][0];  // reuse xs as [64][68] transpose buffer
    __syncthreads();
#pragma unroll
    for (int r = 0; r < 4; ++r)
#pragma unroll
      for (int c = 0; c < 4; ++c)
        tt[(size_t)(tx + 16 * c) * 68 + ty * 4 + r] = cv[r][c];
    __syncthreads();
#pragma unroll
    for (int t = 0; t < 4; ++t) {
      const int cr = tid >> 2;               // 0..63 (col of C = row of CT)
      const int i4 = (tid & 3) * 4 + t * 16; // 0..60
      const float4 v = *reinterpret_cast<const float4*>(&tt[(size_t)cr * 68 + i4]);
      *reinterpret_cast<float4*>(&CT[(size_t)(j0 + cr) * N + i0 + i4]) = v;
    }
  }
}

// ---------------- softmin row body: -eps * LSE_j( logw + (h[j]-C[row][j])/eps ) ----------------
template <int E, bool AVG>
__device__ __forceinline__ void softmin_row(
    const float* __restrict__ Crow, const float* __restrict__ h,
    const float logw, const float inv_eps, const float neg_eps,
    const float* __restrict__ oldv, const int row,
    float* __restrict__ out, float* red)
{
  const int tid = threadIdx.x;
  float a[E];
  constexpr int Q = E / 4;
#pragma unroll
  for (int q = 0; q < Q; ++q) {
    const int j4 = (tid + q * 256) * 4;
    const float4 c4 = *reinterpret_cast<const float4*>(&Crow[j4]);
    const float4 h4 = *reinterpret_cast<const float4*>(&h[j4]);
    a[q * 4 + 0] = fmaf(h4.x - c4.x, inv_eps, logw);
    a[q * 4 + 1] = fmaf(h4.y - c4.y, inv_eps, logw);
    a[q * 4 + 2] = fmaf(h4.z - c4.z, inv_eps, logw);
    a[q * 4 + 3] = fmaf(h4.w - c4.w, inv_eps, logw);
  }
  float m = a[0];
#pragma unroll
  for (int e = 1; e < E; ++e) m = fmaxf(m, a[e]);
#pragma unroll
  for (int off = 32; off; off >>= 1) m = fmaxf(m, __shfl_xor(m, off));
  const int wv = tid >> 6, ln = tid & 63;
  if (ln == 0) red[wv] = m;
  __syncthreads();
  m = fmaxf(fmaxf(red[0], red[1]), fmaxf(red[2], red[3]));
  float s = 0.f;
#pragma unroll
  for (int e = 0; e < E; ++e) s += __expf(a[e] - m);
#pragma unroll
  for (int off = 32; off; off >>= 1) s += __shfl_xor(s, off);
  if (ln == 0) red[4 + wv] = s;
  __syncthreads();
  if (tid == 0) {
    const float S = red[4] + red[5] + red[6] + red[7];
    float v = neg_eps * (m + __logf(S));
    if (AVG) v = 0.5f * (oldv[row] + v);
    out[row] = v;
  }
}

template <int E, bool AVG>
__global__ __launch_bounds__(256) void softmin1_kernel(
    const float* __restrict__ C, const float* __restrict__ h,
    const float* __restrict__ oldv, float* __restrict__ out,
    float logw, int ld, float inv_eps, float neg_eps)
{
  __shared__ float red[8];
  softmin_row<E, AVG>(C + (size_t)blockIdx.x * ld, h, logw, inv_eps, neg_eps,
                      oldv, blockIdx.x, out, red);
}

// two fused passes sharing row length E*256
template <int E, bool AVG>
__global__ __launch_bounds__(256) void softmin2_kernel(
    int nA,
    const float* __restrict__ CA, const float* __restrict__ hA,
    const float* __restrict__ oldA, float* __restrict__ outA, float lwA, int ldA,
    const float* __restrict__ CB, const float* __restrict__ hB,
    const float* __restrict__ oldB, float* __restrict__ outB, float lwB, int ldB,
    float inv_eps, float neg_eps)
{
  __shared__ float red[8];
  const int bid = blockIdx.x;
  if (bid < nA) {
    softmin_row<E, AVG>(CA + (size_t)bid * ldA, hA, lwA, inv_eps, neg_eps,
                        oldA, bid, outA, red);
  } else {
    const int r = bid - nA;
    softmin_row<E, AVG>(CB + (size_t)r * ldB, hB, lwB, inv_eps, neg_eps,
                        oldB, r, outB, red);
  }
}

__global__ void zero_kernel(float* __restrict__ p, int n)
{
  const int i = blockIdx.x * 256 + threadIdx.x;
  if (i < n) p[i] = 0.f;
}

__global__ __launch_bounds__(256) void finalize_kernel(
    const float* __restrict__ fxy1, const float* __restrict__ gxy1, const float* __restrict__ gyy1,
    const float* __restrict__ fxy2, const float* __restrict__ gxy2, const float* __restrict__ gyy2,
    float* __restrict__ out)
{
  const int tid = threadIdx.x;
  float v[6] = {0.f, 0.f, 0.f, 0.f, 0.f, 0.f};
  for (int i = tid; i < 4096; i += 256) { v[0] += fxy1[i]; v[3] += fxy2[i]; }
  for (int i = tid; i < 2048; i += 256) {
    v[1] += gxy1[i]; v[2] += gyy1[i];
    v[4] += gxy2[i]; v[5] += gyy2[i];
  }
  __shared__ float sh[6][4];
  const int wv = tid >> 6, ln = tid & 63;
#pragma unroll
  for (int q = 0; q < 6; ++q) {
    float s = v[q];
#pragma unroll
    for (int off = 32; off; off >>= 1) s += __shfl_xor(s, off);
    if (ln == 0) sh[q][wv] = s;
  }
  __syncthreads();
  if (tid == 0) {
    float t[6];
#pragma unroll
    for (int q = 0; q < 6; ++q) t[q] = sh[q][0] + sh[q][1] + sh[q][2] + sh[q][3];
    const float d1 = t[0] * (1.f / 4096.f) + (t[1] - t[2]) * (1.f / 2048.f);
    const float d2 = t[3] * (1.f / 4096.f) + (t[4] - t[5]) * (1.f / 2048.f);
    const float z = 0.1f * (d2 - d1);
    out[0] = 1.f / (1.f + expf(-z));
  }
}

extern "C" void kernel_launch(void* const* d_in, const int* in_sizes, int n_in,
                              void* d_out, int out_size, void* d_ws, size_t ws_size,
                              hipStream_t stream)
{
  const float* d  = (const float*)d_in[0];   // [4096][768]
  const float* s1 = (const float*)d_in[1];   // [2048][768]
  const float* s2 = (const float*)d_in[2];   // [2048][768]
  const float* Mw = (const float*)d_in[3];   // [768][128]
  float* out = (float*)d_out;
  float* ws = (float*)d_ws;

  const int N = 4096, Mn = 2048;
  size_t off = 0;
  float* td  = ws + off; off += (size_t)N * 128;
  float* t1  = ws + off; off += (size_t)Mn * 128;
  float* t2  = ws + off; off += (size_t)Mn * 128;
  float* nd  = ws + off; off += N;
  float* n1  = ws + off; off += Mn;
  float* n2  = ws + off; off += Mn;
  float* f0  = ws + off; off += N;
  float* f1  = ws + off; off += N;
  float* g0  = ws + off; off += Mn;
  float* g1  = ws + off; off += Mn;
  float* gy0 = ws + off; off += Mn;
  float* gy1 = ws + off; off += Mn;
  float* fxy1 = ws + off; off += N;
  float* gxy1 = ws + off; off += Mn;
  float* gyy1 = ws + off; off += Mn;
  float* fxy2 = ws + off; off += N;
  float* gxy2 = ws + off; off += Mn;
  float* gyy2 = ws + off; off += Mn;
  float* Cxy = ws + off; off += (size_t)N * Mn;
  float* Cyx = ws + off; off += (size_t)Mn * N;
  float* Cyy = ws + off; off += (size_t)Mn * Mn;
  // total ~22.1M floats ~= 85MB of d_ws

  // eps schedule: geomloss annealing, computed in double then cast (matches numpy)
  float eps_l[64]; int ne = 0;
  {
    double e = 1024.0;               // DIAM**P = 32**2
    const double tgt = 0.05 * 0.05;  // BLUR**P
    const double sc = 0.8 * 0.8;     // SCALING**P
    while (e > tgt && ne < 60) { eps_l[ne++] = (float)e; e *= sc; }
    eps_l[ne++] = (float)tgt;        // 30 entries
  }
  const float loga = (float)(-log((double)N));
  const float logb = (float)(-log((double)Mn));

  transform_kernel<<<N / 32, 256, 0, stream>>>(d, Mw, td);
  transform_kernel<<<Mn / 32, 256, 0, stream>>>(s1, Mw, t1);
  transform_kernel<<<Mn / 32, 256, 0, stream>>>(s2, Mw, t2);
  rownorm_kernel<<<N / 4, 256, 0, stream>>>(td, nd, N);
  rownorm_kernel<<<Mn / 4, 256, 0, stream>>>(t1, n1, Mn);
  rownorm_kernel<<<Mn / 4, 256, 0, stream>>>(t2, n2, Mn);

  for (int dv = 0; dv < 2; ++dv) {
    const float* y  = dv ? t2 : t1;
    const float* nv = dv ? n2 : n1;
    float* fxy = dv ? fxy2 : fxy1;
    float* gxy = dv ? gxy2 : gxy1;
    float* gyy = dv ? gyy2 : gyy1;

    dim3 gA(N / 64, Mn / 64);
    cost_kernel<<<gA, 256, 0, stream>>>(td, y, nd, nv, Cxy, Cyx, N, Mn);
    dim3 gB(Mn / 64, Mn / 64);
    cost_kernel<<<gB, 256, 0, stream>>>(y, y, nv, nv, Cyy, nullptr, Mn, Mn);
    // zero f0,f1,g0,g1,gy0,gy1 (contiguous 2N+4Mn floats)
    zero_kernel<<<(2 * N + 4 * Mn + 255) / 256, 256, 0, stream>>>(f0, 2 * N + 4 * Mn);

    float *fc = f0, *fn = f1, *gc = g0, *gn = g1, *yc = gy0, *yn = gy1;
    for (int it = 0; it < ne; ++it) {
      const float e = eps_l[it];
      const float ie = 1.f / e, nege = -e;
      // ft (rows of Cxy, h=g) fused with gy-update (rows of Cyy, h=gy)
      softmin2_kernel<8, true><<<N + Mn, 256, 0, stream>>>(
          N, Cxy, gc, fc, fn, logb, Mn,
          Cyy, yc, yc, yn, logb, Mn, ie, nege);
      // gt (rows of Cyx, h=f_old)
      softmin1_kernel<16, true><<<Mn, 256, 0, stream>>>(
          Cyx, fc, gc, gn, loga, N, ie, nege);
      float* t;
      t = fc; fc = fn; fn = t;
      t = gc; gc = gn; gn = t;
      t = yc; yc = yn; yn = t;
    }
    // final extrapolation at eps_last (no averaging)
    const float e = eps_l[ne - 1];
    const float ie = 1.f / e, nege = -e;
    softmin2_kernel<8, false><<<N + Mn, 256, 0, stream>>>(
        N, Cxy, gc, nullptr, fxy, logb, Mn,
        Cyy, yc, nullptr, gyy, logb, Mn, ie, nege);
    softmin1_kernel<16, false><<<Mn, 256, 0, stream>>>(
        Cyx, fc, nullptr, gxy, loga, N, ie, nege);
  }

  finalize_kernel<<<1, 256, 0, stream>>>(fxy1, gxy1, gyy1, fxy2, gxy2, gyy2, out);
  (void)in_sizes; (void)n_in; (void)out_size; (void)ws_size;
}

// Round 2
// 717.923 us; speedup vs baseline: 2.1967x; 2.1967x over previous
//
#include <hip/hip_runtime.h>
#include <math.h>

typedef unsigned short u16;

#define NE 30
static constexpr float QMAX = 160.0f;
static constexpr float QS   = 65535.0f / QMAX;
static constexpr float LOGA = -8.3177661667193430f;   // -log(4096)
static constexpr float LOGB = -7.6246189861593985f;   // -log(2048)

// ---- ws layout (float units) ----
static constexpr size_t OFF_T   = 0;                  // td(4096x128), t1, t2 : 1,048,576
static constexpr size_t OFF_N   = 1048576;            // nd(4096), n1(2048), n2(2048)
static constexpr size_t OFF_POT = OFF_N + 8192;       // 2 dv x [f0,f1(4096ea), g0,g1,gy0,gy1(2048ea)] = 32768
static constexpr size_t OFF_OUT = OFF_POT + 32768;    // 2 dv x [fxy 4096, gxy 2048, gyy 2048] = 16384
static constexpr size_t OFF_CQ  = OFF_OUT + 16384;    // u16 C area (also aliased as fp32 transform partials)
// u16-unit offsets inside CQ area:
static constexpr size_t CQ_YX = 8388608;    // Cyx after Cxy (4096*2048)
static constexpr size_t CQ_YY = 16777216;   // Cyy after Cyx
static constexpr size_t CQ_DV = 20971520;   // per-dv stride (u16)

__device__ __forceinline__ u16 quant160(float cv) {
  return (u16)(unsigned int)fminf(fmaf(cv, QS, 0.5f), 65535.0f);
}

// ---------------- fused transform with split-K: P[ks] += X @ M over k-range ----------------
__global__ __launch_bounds__(256, 1) void transform_kernel(
    const float* __restrict__ d, const float* __restrict__ s1,
    const float* __restrict__ s2, const float* __restrict__ Mw,
    float* __restrict__ ws)
{
  __shared__ float Xs[128 * 40];   // [row][k] stride 40
  __shared__ float Ms[32 * 132];   // [k][col] stride 132
  const int tid  = threadIdx.x;
  const int tile = blockIdx.x & 63;
  const int ks   = blockIdx.x >> 6;
  const float* Xb; int rbase;
  if (tile < 32)      { Xb = d;  rbase = tile * 128; }
  else if (tile < 48) { Xb = s1; rbase = (tile - 32) * 128; }
  else                { Xb = s2; rbase = (tile - 48) * 128; }
  const int trow  = tid >> 4;          // 0..15 -> rows trow*8..+7
  const int tcol4 = (tid & 15) * 4;    // cols tcol4..+3 and 64+tcol4..+3
  float acc[8][8];
#pragma unroll
  for (int r = 0; r < 8; ++r)
#pragma unroll
    for (int c = 0; c < 8; ++c) acc[r][c] = 0.f;

  for (int ch = 0; ch < 6; ++ch) {
    const int k0 = ks * 192 + ch * 32;
#pragma unroll
    for (int t = 0; t < 4; ++t) {          // stage X: 128 rows x 32 k
      const int fi = tid + t * 256;
      const int row = fi >> 3, k4 = (fi & 7) * 4;
      const float4 v = *reinterpret_cast<const float4*>(&Xb[(size_t)(rbase + row) * 768 + k0 + k4]);
      *reinterpret_cast<float4*>(&Xs[row * 40 + k4]) = v;
    }
#pragma unroll
    for (int t = 0; t < 4; ++t) {          // stage M: 32 k x 128 cols
      const int fi = tid + t * 256;
      const int kk = fi >> 5, c4 = (fi & 31) * 4;
      const float4 v = *reinterpret_cast<const float4*>(&Mw[(size_t)(k0 + kk) * 128 + c4]);
      *reinterpret_cast<float4*>(&Ms[kk * 132 + c4]) = v;
    }
    __syncthreads();
#pragma unroll
    for (int kq = 0; kq < 8; ++kq) {
      float xk[8][4];
#pragma unroll
      for (int r = 0; r < 8; ++r) {
        const float4 xq = *reinterpret_cast<const float4*>(&Xs[(trow * 8 + r) * 40 + kq * 4]);
        xk[r][0] = xq.x; xk[r][1] = xq.y; xk[r][2] = xq.z; xk[r][3] = xq.w;
      }
#pragma unroll
      for (int kk = 0; kk < 4; ++kk) {
        const float4 m0 = *reinterpret_cast<const float4*>(&Ms[(kq * 4 + kk) * 132 + tcol4]);
        const float4 m1 = *reinterpret_cast<const float4*>(&Ms[(kq * 4 + kk) * 132 + 64 + tcol4]);
#pragma unroll
        for (int r = 0; r < 8; ++r) {
          const float x = xk[r][kk];
          acc[r][0] = fmaf(x, m0.x, acc[r][0]);
          acc[r][1] = fmaf(x, m0.y, acc[r][1]);
          acc[r][2] = fmaf(x, m0.z, acc[r][2]);
          acc[r][3] = fmaf(x, m0.w, acc[r][3]);
          acc[r][4] = fmaf(x, m1.x, acc[r][4]);
          acc[r][5] = fmaf(x, m1.y, acc[r][5]);
          acc[r][6] = fmaf(x, m1.z, acc[r][6]);
          acc[r][7] = fmaf(x, m1.w, acc[r][7]);
        }
      }
    }
    __syncthreads();
  }
  float* P = ws + OFF_CQ + (size_t)ks * 1048576;
  const int grow = tile * 128 + trow * 8;
#pragma unroll
  for (int r = 0; r < 8; ++r) {
    const float4 v0 = make_float4(acc[r][0], acc[r][1], acc[r][2], acc[r][3]);
    const float4 v1 = make_float4(acc[r][4], acc[r][5], acc[r][6], acc[r][7]);
    *reinterpret_cast<float4*>(&P[(size_t)(grow + r) * 128 + tcol4]) = v0;
    *reinterpret_cast<float4*>(&P[(size_t)(grow + r) * 128 + 64 + tcol4]) = v1;
  }
}

__global__ __launch_bounds__(256) void reduce4_kernel(float* __restrict__ ws)
{
  const size_t idx = (size_t)blockIdx.x * 256 + threadIdx.x;   // float4 units
  const float4* p = reinterpret_cast<const float4*>(ws + OFF_CQ);
  const float4 a = p[idx], b = p[idx + 262144], c = p[idx + 524288], d4 = p[idx + 786432];
  float4 o;
  o.x = a.x + b.x + c.x + d4.x;
  o.y = a.y + b.y + c.y + d4.y;
  o.z = a.z + b.z + c.z + d4.z;
  o.w = a.w + b.w + c.w + d4.w;
  reinterpret_cast<float4*>(ws + OFF_T)[idx] = o;
}

// ---------------- row squared norms (8192 rows of T) ----------------
__global__ __launch_bounds__(256) void rownorm_kernel(float* __restrict__ ws)
{
  const int wv = threadIdx.x >> 6, ln = threadIdx.x & 63;
  const int row = blockIdx.x * 4 + wv;
  const float* T = ws + OFF_T;
  const float2 v = reinterpret_cast<const float2*>(T + (size_t)row * 128)[ln];
  float s = fmaf(v.x, v.x, v.y * v.y);
#pragma unroll
  for (int off = 32; off; off >>= 1) s += __shfl_xor(s, off);
  if (ln == 0) ws[OFF_N + row] = s;
}

// ---------------- cost matrix -> u16 quantized (optionally transposed copy) ----------------
__global__ __launch_bounds__(256) void cost_kernel(
    const float* __restrict__ X, const float* __restrict__ Y,
    const float* __restrict__ nx, const float* __restrict__ ny,
    u16* __restrict__ C, u16* __restrict__ CT,
    int N, int Mc)
{
  __shared__ __align__(16) float xs[64][68];
  __shared__ __align__(16) float ys[64][68];
  const int tid = threadIdx.x;
  const int i0 = blockIdx.x * 64;
  const int j0 = blockIdx.y * 64;
  const int tx = tid & 15;
  const int ty = tid >> 4;
  float acc[4][4];
#pragma unroll
  for (int r = 0; r < 4; ++r)
#pragma unroll
    for (int c = 0; c < 4; ++c) acc[r][c] = 0.f;

  for (int kc = 0; kc < 128; kc += 64) {
#pragma unroll
    for (int t = 0; t < 4; ++t) {
      const int fi = tid + t * 256;
      const int row = fi >> 4;
      const int k4 = (fi & 15) * 4;
      *reinterpret_cast<float4*>(&xs[row][k4]) =
          *reinterpret_cast<const float4*>(&X[(size_t)(i0 + row) * 128 + kc + k4]);
      *reinterpret_cast<float4*>(&ys[row][k4]) =
          *reinterpret_cast<const float4*>(&Y[(size_t)(j0 + row) * 128 + kc + k4]);
    }
    __syncthreads();
#pragma unroll
    for (int k = 0; k < 64; k += 4) {
      float4 xv[4], yv[4];
#pragma unroll
      for (int r = 0; r < 4; ++r)
        xv[r] = *reinterpret_cast<const float4*>(&xs[ty * 4 + r][k]);
#pragma unroll
      for (int c = 0; c < 4; ++c)
        yv[c] = *reinterpret_cast<const float4*>(&ys[tx + 16 * c][k]);
#pragma unroll
      for (int r = 0; r < 4; ++r)
#pragma unroll
        for (int c = 0; c < 4; ++c) {
          acc[r][c] = fmaf(xv[r].x, yv[c].x, acc[r][c]);
          acc[r][c] = fmaf(xv[r].y, yv[c].y, acc[r][c]);
          acc[r][c] = fmaf(xv[r].z, yv[c].z, acc[r][c]);
          acc[r][c] = fmaf(xv[r].w, yv[c].w, acc[r][c]);
        }
    }
    __syncthreads();
  }
  float vnx[4], vny[4];
#pragma unroll
  for (int r = 0; r < 4; ++r) vnx[r] = nx[i0 + ty * 4 + r];
#pragma unroll
  for (int c = 0; c < 4; ++c) vny[c] = ny[j0 + tx + 16 * c];
  float cv[4][4];
#pragma unroll
  for (int r = 0; r < 4; ++r)
#pragma unroll
    for (int c = 0; c < 4; ++c) {
      const float sq = vnx[r] + vny[c] - 2.f * acc[r][c];
      cv[r][c] = 0.5f * fmaxf(sq, 0.f);
      C[(size_t)(i0 + ty * 4 + r) * Mc + (j0 + tx + 16 * c)] = quant160(cv[r][c]);
    }
  if (CT != nullptr) {
    float* tt = &xs[0][0];
    __syncthreads();
#pragma unroll
    for (int r = 0; r < 4; ++r)
#pragma unroll
      for (int c = 0; c < 4; ++c)
        tt[(size_t)(tx + 16 * c) * 68 + ty * 4 + r] = cv[r][c];
    __syncthreads();
#pragma unroll
    for (int t = 0; t < 4; ++t) {
      const int cr = tid >> 2;
      const int i4 = (tid & 3) * 4 + t * 16;
      const float4 v = *reinterpret_cast<const float4*>(&tt[(size_t)cr * 68 + i4]);
      ushort4 u;
      u.x = quant160(v.x); u.y = quant160(v.y); u.z = quant160(v.z); u.w = quant160(v.w);
      *reinterpret_cast<ushort4*>(&CT[(size_t)(j0 + cr) * N + i0 + i4]) = u;
    }
  }
}

// ---------------- wave-per-row softmin on u16-quantized C ----------------
template <int K8>
__device__ __forceinline__ void softmin_wave(
    const u16* __restrict__ Crow, const float* __restrict__ h,
    const float lw, const float ie, const float nege, const float qie,
    const float* __restrict__ oldv, float* __restrict__ o,
    const int row, const int avg, const int ln)
{
  float a[K8 * 8];
#pragma unroll
  for (int k = 0; k < K8; ++k) {
    const int j8 = (ln + k * 64) * 8;
    const uint4 cq = *reinterpret_cast<const uint4*>(&Crow[j8]);
    const float4 h0 = *reinterpret_cast<const float4*>(&h[j8]);
    const float4 h1 = *reinterpret_cast<const float4*>(&h[j8 + 4]);
    float* aa = a + k * 8;
    aa[0] = fmaf(h0.x, ie, lw) - (float)(cq.x & 0xffffu) * qie;
    aa[1] = fmaf(h0.y, ie, lw) - (float)(cq.x >> 16)     * qie;
    aa[2] = fmaf(h0.z, ie, lw) - (float)(cq.y & 0xffffu) * qie;
    aa[3] = fmaf(h0.w, ie, lw) - (float)(cq.y >> 16)     * qie;
    aa[4] = fmaf(h1.x, ie, lw) - (float)(cq.z & 0xffffu) * qie;
    aa[5] = fmaf(h1.y, ie, lw) - (float)(cq.z >> 16)     * qie;
    aa[6] = fmaf(h1.z, ie, lw) - (float)(cq.w & 0xffffu) * qie;
    aa[7] = fmaf(h1.w, ie, lw) - (float)(cq.w >> 16)     * qie;
  }
  float m = a[0];
#pragma unroll
  for (int i = 1; i < K8 * 8; ++i) m = fmaxf(m, a[i]);
#pragma unroll
  for (int off = 32; off; off >>= 1) m = fmaxf(m, __shfl_xor(m, off));
  float s = 0.f;
#pragma unroll
  for (int i = 0; i < K8 * 8; ++i) s += __expf(a[i] - m);
#pragma unroll
  for (int off = 32; off; off >>= 1) s += __shfl_xor(s, off);
  if (ln == 0) {
    float v = nege * (m + __logf(s));
    if (avg) v = 0.5f * (oldv[row] + v);
    o[row] = v;
  }
}

// one launch = one full Sinkhorn iteration for BOTH divergences (16384 wave-tasks)
__global__ __launch_bounds__(256, 2) void sinkhorn_iter_kernel(
    float* __restrict__ ws, const float ie, const float nege, const float qie,
    const int cur, const int fin)
{
  const int wv = threadIdx.x >> 6, ln = threadIdx.x & 63;
  const int task = blockIdx.x * 4 + wv;
  const int dv = task >> 13;
  const int r = task & 8191;
  float* pot  = ws + OFF_POT + dv * 16384;
  float* outv = ws + OFF_OUT + dv * 8192;
  const u16* cq = reinterpret_cast<const u16*>(ws + OFF_CQ) + (size_t)dv * CQ_DV;
  float* fc = pot + cur * 4096;
  float* fn = pot + (cur ^ 1) * 4096;
  float* gc = pot + 8192 + cur * 2048;
  float* gn = pot + 8192 + (cur ^ 1) * 2048;
  float* yc = pot + 12288 + cur * 2048;
  float* yn = pot + 12288 + (cur ^ 1) * 2048;
  if (r < 4096) {          // ft: rows of Cxy, h = g
    softmin_wave<4>(cq + (size_t)r * 2048, gc, LOGB, ie, nege, qie,
                    fc, fin ? outv : fn, r, !fin, ln);
  } else if (r < 6144) {   // gy: rows of Cyy, h = gy
    const int rr = r - 4096;
    softmin_wave<4>(cq + CQ_YY + (size_t)rr * 2048, yc, LOGB, ie, nege, qie,
                    yc, fin ? (outv + 6144) : yn, rr, !fin, ln);
  } else {                 // gt: rows of Cyx, h = f
    const int rr = r - 6144;
    softmin_wave<8>(cq + CQ_YX + (size_t)rr * 4096, fc, LOGA, ie, nege, qie,
                    gc, fin ? (outv + 4096) : gn, rr, !fin, ln);
  }
}

__global__ void init_pot_kernel(float* __restrict__ ws)
{
  const int i = blockIdx.x * 256 + threadIdx.x;
  if (i < 32768) ws[OFF_POT + i] = 0.f;
}

__global__ __launch_bounds__(256) void finalize_kernel(
    const float* __restrict__ ws, float* __restrict__ out)
{
  const float* ov = ws + OFF_OUT;
  const int tid = threadIdx.x;
  float v[6] = {0.f, 0.f, 0.f, 0.f, 0.f, 0.f};
  for (int i = tid; i < 4096; i += 256) { v[0] += ov[i]; v[3] += ov[8192 + i]; }
  for (int i = tid; i < 2048; i += 256) {
    v[1] += ov[4096 + i]; v[2] += ov[6144 + i];
    v[4] += ov[8192 + 4096 + i]; v[5] += ov[8192 + 6144 + i];
  }
  __shared__ float sh[6][4];
  const int wv = tid >> 6, ln = tid & 63;
#pragma unroll
  for (int q = 0; q < 6; ++q) {
    float s = v[q];
#pragma unroll
    for (int off = 32; off; off >>= 1) s += __shfl_xor(s, off);
    if (ln == 0) sh[q][wv] = s;
  }
  __syncthreads();
  if (tid == 0) {
    float t[6];
#pragma unroll
    for (int q = 0; q < 6; ++q) t[q] = sh[q][0] + sh[q][1] + sh[q][2] + sh[q][3];
    const float d1 = t[0] * (1.f / 4096.f) + (t[1] - t[2]) * (1.f / 2048.f);
    const float d2 = t[3] * (1.f / 4096.f) + (t[4] - t[5]) * (1.f / 2048.f);
    const float z = 0.1f * (d2 - d1);
    out[0] = 1.f / (1.f + expf(-z));
  }
}

extern "C" void kernel_launch(void* const* d_in, const int* in_sizes, int n_in,
                              void* d_out, int out_size, void* d_ws, size_t ws_size,
                              hipStream_t stream)
{
  const float* d  = (const float*)d_in[0];   // [4096][768]
  const float* s1 = (const float*)d_in[1];   // [2048][768]
  const float* s2 = (const float*)d_in[2];   // [2048][768]
  const float* Mw = (const float*)d_in[3];   // [768][128]
  float* out = (float*)d_out;
  float* ws = (float*)d_ws;

  // eps schedule (matches geomloss annealing, double math then f32 cast)
  float eps_l[NE];
  {
    double e = 1024.0;
    const double sc = 0.8 * 0.8;
    for (int k = 0; k < NE - 1; ++k) { eps_l[k] = (float)e; e *= sc; }
    eps_l[NE - 1] = (float)(0.05 * 0.05);
  }

  float* td = ws + OFF_T;
  float* t1 = td + 524288;
  float* t2 = t1 + 262144;
  float* nd = ws + OFF_N;
  float* n1 = nd + 4096;
  float* n2 = n1 + 2048;
  u16* cq0  = (u16*)(ws + OFF_CQ);
  u16* cxy1 = cq0;
  u16* cyx1 = cq0 + CQ_YX;
  u16* cyy1 = cq0 + CQ_YY;
  u16* cxy2 = cq0 + CQ_DV;
  u16* cyx2 = cxy2 + CQ_YX;
  u16* cyy2 = cxy2 + CQ_YY;

  // 1) fused transform (split-K partials aliased into CQ area), reduce, norms
  transform_kernel<<<256, 256, 0, stream>>>(d, s1, s2, Mw, ws);
  reduce4_kernel<<<1024, 256, 0, stream>>>(ws);
  rownorm_kernel<<<2048, 256, 0, stream>>>(ws);

  // 2) quantized cost matrices for both divergences
  dim3 gA(64, 32), gB(32, 32);
  cost_kernel<<<gA, 256, 0, stream>>>(td, t1, nd, n1, cxy1, cyx1, 4096, 2048);
  cost_kernel<<<gB, 256, 0, stream>>>(t1, t1, n1, n1, cyy1, nullptr, 2048, 2048);
  cost_kernel<<<gA, 256, 0, stream>>>(td, t2, nd, n2, cxy2, cyx2, 4096, 2048);
  cost_kernel<<<gB, 256, 0, stream>>>(t2, t2, n2, n2, cyy2, nullptr, 2048, 2048);

  // 3) Sinkhorn loop: one launch per iteration (both dv, all 3 softmin roles)
  init_pot_kernel<<<128, 256, 0, stream>>>(ws);
  int cur = 0;
  for (int it = 0; it <= NE; ++it) {
    const int fin = (it == NE);
    const float e = eps_l[fin ? NE - 1 : it];
    const float ie = 1.0f / e;
    sinkhorn_iter_kernel<<<4096, 256, 0, stream>>>(ws, ie, -e, (QMAX / 65535.0f) * ie, cur, fin);
    if (!fin) cur ^= 1;
  }

  finalize_kernel<<<1, 256, 0, stream>>>(ws, out);
  (void)in_sizes; (void)n_in; (void)out_size; (void)ws_size;
}

// Round 3
// 663.024 us; speedup vs baseline: 2.3785x; 1.0828x over previous
//
#include <hip/hip_runtime.h>
#include <math.h>

typedef unsigned short u16;
typedef unsigned int u32;
typedef __attribute__((ext_vector_type(8))) short bf16x8;
typedef __attribute__((ext_vector_type(4))) float f32x4;

#define NE 30
static constexpr float QMAX  = 160.0f;
static constexpr float QS    = 65535.0f / QMAX;
static constexpr float LOGA  = -8.3177661667193430f;   // -log(4096)
static constexpr float LOGB  = -7.6246189861593985f;   // -log(2048)
static constexpr float LOG2E = 1.4426950408889634f;
static constexpr float LN2   = 0.6931471805599453f;

// ---- ws layout (float units) ----
// THI u16[8192*128] at 0 (=524288 floats), TLO after it.
static constexpr size_t OFF_MT  = 1048576;   // Mt hi/lo u16[2*768*128] = 98304 floats
static constexpr size_t OFF_N   = 1146880;   // norms[8192]
static constexpr size_t OFF_POT = 1155072;   // 2 dv x 16384
static constexpr size_t OFF_OUT = 1187840;   // 2 dv x 8192
static constexpr size_t OFF_CQ  = 1204224;   // u16 C area
static constexpr size_t CQ_YX = 8388608;     // u16 units
static constexpr size_t CQ_YY = 16777216;
static constexpr size_t CQ_DV = 20971520;

__device__ __forceinline__ float fexp2(float x) {
#if __has_builtin(__builtin_amdgcn_exp2f)
  return __builtin_amdgcn_exp2f(x);
#else
  return exp2f(x);
#endif
}
__device__ __forceinline__ float flog2(float x) {
#if __has_builtin(__builtin_amdgcn_logf)
  return __builtin_amdgcn_logf(x);
#else
  return __log2f(x);
#endif
}

__device__ __forceinline__ u16 quant160(float cv) {
  return (u16)(u32)fminf(fmaf(cv, QS, 0.5f), 65535.0f);
}

// exact split x = hi + lo (both bf16-truncations); x - as_float(hi) is exact.
__device__ __forceinline__ void split1(float x, u16& h, u16& l) {
  const u32 u = __float_as_uint(x);
  const u32 hb = u & 0xffff0000u;
  const float xl = x - __uint_as_float(hb);
  h = (u16)(hb >> 16);
  l = (u16)(__float_as_uint(xl) >> 16);
}

__device__ __forceinline__ void splitAB(const float4 p, const float4 q,
                                        bf16x8& h, bf16x8& l) {
  const float pf[8] = {p.x, p.y, p.z, p.w, q.x, q.y, q.z, q.w};
#pragma unroll
  for (int i = 0; i < 8; ++i) {
    u16 hh, ll;
    split1(pf[i], hh, ll);
    h[i] = (short)hh;
    l[i] = (short)ll;
  }
}

// ---------------- prep M: transpose+split into B-frag layout [ks][g][n][e] ----------------
__global__ __launch_bounds__(256) void prep_m_kernel(
    const float* __restrict__ Mw, float* __restrict__ ws)
{
  const int id = blockIdx.x * 256 + threadIdx.x;   // 12288 = 24 ks x 4 g x 128 n
  const int ks = id >> 9;
  const int g  = (id >> 7) & 3;
  const int n  = id & 127;
  u16* mthi = (u16*)(ws + OFF_MT);
  u16* mtlo = mthi + 98304;
  bf16x8 h, l;
#pragma unroll
  for (int e = 0; e < 8; ++e) {
    const float x = Mw[(size_t)(ks * 32 + g * 8 + e) * 128 + n];
    u16 hh, ll;
    split1(x, hh, ll);
    h[e] = (short)hh;
    l[e] = (short)ll;
  }
  *reinterpret_cast<bf16x8*>(mthi + (size_t)id * 8) = h;
  *reinterpret_cast<bf16x8*>(mtlo + (size_t)id * 8) = l;
}

// ---------------- MFMA transform: T = X @ M (bf16 hi/lo, fp32 acc); emits THI/TLO + norms ----------------
__global__ __launch_bounds__(256, 1) void transform_kernel(
    const float* __restrict__ d, const float* __restrict__ s1,
    const float* __restrict__ s2, float* __restrict__ ws)
{
  __shared__ __align__(16) float eb[64 * 132];
  const int tid = threadIdx.x;
  const int w = tid >> 6, ln = tid & 63;
  const int lr = ln & 15, lg = ln >> 4;
  const int b = blockIdx.x;
  const float* Xb; int r0;
  if (b < 32)      { Xb = d;  r0 = b * 128; }
  else if (b < 48) { Xb = s1; r0 = (b - 32) * 128; }
  else             { Xb = s2; r0 = (b - 48) * 128; }
  const int rbg = b * 128;
  const u16* mthi = (const u16*)(ws + OFF_MT);
  const u16* mtlo = mthi + 98304;

  f32x4 acc[2][8];
  const f32x4 zero = {0.f, 0.f, 0.f, 0.f};
#pragma unroll
  for (int mt = 0; mt < 2; ++mt)
#pragma unroll
    for (int nt = 0; nt < 8; ++nt) acc[mt][nt] = zero;

  for (int ks = 0; ks < 24; ++ks) {
    bf16x8 ah[2], al[2];
#pragma unroll
    for (int mt = 0; mt < 2; ++mt) {
      const float* xp = Xb + (size_t)(r0 + w * 32 + mt * 16 + lr) * 768 + ks * 32 + lg * 8;
      const float4 p = *reinterpret_cast<const float4*>(xp);
      const float4 q = *reinterpret_cast<const float4*>(xp + 4);
      splitAB(p, q, ah[mt], al[mt]);
    }
#pragma unroll
    for (int nt = 0; nt < 8; ++nt) {
      const size_t bo = ((size_t)(ks * 4 + lg) * 128 + nt * 16 + lr) * 8;
      const bf16x8 bh = *reinterpret_cast<const bf16x8*>(mthi + bo);
      const bf16x8 bl = *reinterpret_cast<const bf16x8*>(mtlo + bo);
#pragma unroll
      for (int mt = 0; mt < 2; ++mt) {
        acc[mt][nt] = __builtin_amdgcn_mfma_f32_16x16x32_bf16(ah[mt], bh, acc[mt][nt], 0, 0, 0);
        acc[mt][nt] = __builtin_amdgcn_mfma_f32_16x16x32_bf16(ah[mt], bl, acc[mt][nt], 0, 0, 0);
        acc[mt][nt] = __builtin_amdgcn_mfma_f32_16x16x32_bf16(al[mt], bh, acc[mt][nt], 0, 0, 0);
      }
    }
  }

  // row norms (row = w*32 + mt*16 + lg*4 + reg, partial over cols then 16-lane reduce)
#pragma unroll
  for (int mt = 0; mt < 2; ++mt)
#pragma unroll
    for (int reg = 0; reg < 4; ++reg) {
      float p = 0.f;
#pragma unroll
      for (int nt = 0; nt < 8; ++nt) {
        const float v = acc[mt][nt][reg];
        p = fmaf(v, v, p);
      }
      p += __shfl_xor(p, 1);
      p += __shfl_xor(p, 2);
      p += __shfl_xor(p, 4);
      p += __shfl_xor(p, 8);
      if (lr == 0)
        ws[OFF_N + rbg + w * 32 + mt * 16 + lg * 4 + reg] = p;
    }

  // stage to LDS (two 64-row halves), split+store THI/TLO
  u16* thi = (u16*)ws;
  u16* tlo = thi + 1048576;
  for (int half = 0; half < 2; ++half) {
    if ((w >> 1) == half) {
#pragma unroll
      for (int mt = 0; mt < 2; ++mt)
#pragma unroll
        for (int nt = 0; nt < 8; ++nt)
#pragma unroll
          for (int reg = 0; reg < 4; ++reg)
            eb[((w & 1) * 32 + mt * 16 + lg * 4 + reg) * 132 + nt * 16 + lr] = acc[mt][nt][reg];
    }
    __syncthreads();
    const int rrow = tid >> 2, kg = tid & 3;
    const float* lp = eb + rrow * 132 + kg * 32;
    u16 hs[32], ls[32];
#pragma unroll
    for (int q = 0; q < 8; ++q) {
      const float4 f = *reinterpret_cast<const float4*>(lp + q * 4);
      split1(f.x, hs[q * 4 + 0], ls[q * 4 + 0]);
      split1(f.y, hs[q * 4 + 1], ls[q * 4 + 1]);
      split1(f.z, hs[q * 4 + 2], ls[q * 4 + 2]);
      split1(f.w, hs[q * 4 + 3], ls[q * 4 + 3]);
    }
    const size_t gb = (size_t)(rbg + half * 64 + rrow) * 128 + kg * 32;
#pragma unroll
    for (int q = 0; q < 4; ++q) {
      uint4 hv, lv;
      hv.x = (u32)hs[q * 8 + 0] | ((u32)hs[q * 8 + 1] << 16);
      hv.y = (u32)hs[q * 8 + 2] | ((u32)hs[q * 8 + 3] << 16);
      hv.z = (u32)hs[q * 8 + 4] | ((u32)hs[q * 8 + 5] << 16);
      hv.w = (u32)hs[q * 8 + 6] | ((u32)hs[q * 8 + 7] << 16);
      lv.x = (u32)ls[q * 8 + 0] | ((u32)ls[q * 8 + 1] << 16);
      lv.y = (u32)ls[q * 8 + 2] | ((u32)ls[q * 8 + 3] << 16);
      lv.z = (u32)ls[q * 8 + 4] | ((u32)ls[q * 8 + 5] << 16);
      lv.w = (u32)ls[q * 8 + 6] | ((u32)ls[q * 8 + 7] << 16);
      *reinterpret_cast<uint4*>(thi + gb + q * 8) = hv;
      *reinterpret_cast<uint4*>(tlo + gb + q * 8) = lv;
    }
    __syncthreads();
  }
}

// ---------------- MFMA cost: C[i][j] = 0.5*max(nx+ny-2*x.y,0) -> u16 (+optional CT) ----------------
__global__ __launch_bounds__(256, 1) void cost_kernel(
    const u16* __restrict__ xhi, const u16* __restrict__ xlo,
    const u16* __restrict__ yhi, const u16* __restrict__ ylo,
    const float* __restrict__ nx, const float* __restrict__ ny,
    u16* __restrict__ C, u16* __restrict__ CT, int ldc, int ldct)
{
  __shared__ __align__(16) float eb[64 * 132];
  const int tid = threadIdx.x;
  const int w = tid >> 6, ln = tid & 63;
  const int lr = ln & 15, lg = ln >> 4;
  const int i0 = blockIdx.x * 128, j0 = blockIdx.y * 128;

  f32x4 acc[2][8];
  const f32x4 zero = {0.f, 0.f, 0.f, 0.f};
#pragma unroll
  for (int mt = 0; mt < 2; ++mt)
#pragma unroll
    for (int nt = 0; nt < 8; ++nt) acc[mt][nt] = zero;

#pragma unroll
  for (int ks = 0; ks < 4; ++ks) {
    bf16x8 ah[2], al[2];
#pragma unroll
    for (int mt = 0; mt < 2; ++mt) {
      const size_t xo = (size_t)(i0 + w * 32 + mt * 16 + lr) * 128 + ks * 32 + lg * 8;
      ah[mt] = *reinterpret_cast<const bf16x8*>(xhi + xo);
      al[mt] = *reinterpret_cast<const bf16x8*>(xlo + xo);
    }
#pragma unroll
    for (int nt = 0; nt < 8; ++nt) {
      const size_t yo = (size_t)(j0 + nt * 16 + lr) * 128 + ks * 32 + lg * 8;
      const bf16x8 bh = *reinterpret_cast<const bf16x8*>(yhi + yo);
      const bf16x8 bl = *reinterpret_cast<const bf16x8*>(ylo + yo);
#pragma unroll
      for (int mt = 0; mt < 2; ++mt) {
        acc[mt][nt] = __builtin_amdgcn_mfma_f32_16x16x32_bf16(ah[mt], bh, acc[mt][nt], 0, 0, 0);
        acc[mt][nt] = __builtin_amdgcn_mfma_f32_16x16x32_bf16(ah[mt], bl, acc[mt][nt], 0, 0, 0);
        acc[mt][nt] = __builtin_amdgcn_mfma_f32_16x16x32_bf16(al[mt], bh, acc[mt][nt], 0, 0, 0);
      }
    }
  }

  for (int half = 0; half < 2; ++half) {
    if ((w >> 1) == half) {
#pragma unroll
      for (int mt = 0; mt < 2; ++mt)
#pragma unroll
        for (int nt = 0; nt < 8; ++nt)
#pragma unroll
          for (int reg = 0; reg < 4; ++reg)
            eb[((w & 1) * 32 + mt * 16 + lg * 4 + reg) * 132 + nt * 16 + lr] = acc[mt][nt][reg];
    }
    __syncthreads();
    {  // C rows (row-major)
      const int rrow = tid >> 2, kg = tid & 3;
      const float nxi = nx[i0 + half * 64 + rrow];
      const float* lp = eb + rrow * 132 + kg * 32;
      u16 qs[32];
#pragma unroll
      for (int q = 0; q < 8; ++q) {
        const float4 e4 = *reinterpret_cast<const float4*>(lp + q * 4);
        const float4 n4 = *reinterpret_cast<const float4*>(ny + j0 + kg * 32 + q * 4);
        qs[q * 4 + 0] = quant160(0.5f * fmaxf(nxi + n4.x - 2.f * e4.x, 0.f));
        qs[q * 4 + 1] = quant160(0.5f * fmaxf(nxi + n4.y - 2.f * e4.y, 0.f));
        qs[q * 4 + 2] = quant160(0.5f * fmaxf(nxi + n4.z - 2.f * e4.z, 0.f));
        qs[q * 4 + 3] = quant160(0.5f * fmaxf(nxi + n4.w - 2.f * e4.w, 0.f));
      }
      u16* crow = C + (size_t)(i0 + half * 64 + rrow) * ldc + j0 + kg * 32;
#pragma unroll
      for (int q = 0; q < 4; ++q) {
        uint4 v;
        v.x = (u32)qs[q * 8 + 0] | ((u32)qs[q * 8 + 1] << 16);
        v.y = (u32)qs[q * 8 + 2] | ((u32)qs[q * 8 + 3] << 16);
        v.z = (u32)qs[q * 8 + 4] | ((u32)qs[q * 8 + 5] << 16);
        v.w = (u32)qs[q * 8 + 6] | ((u32)qs[q * 8 + 7] << 16);
        *reinterpret_cast<uint4*>(crow + q * 8) = v;
      }
    }
    if (CT != nullptr) {  // transposed copy
      const int j = tid >> 1, ig = tid & 1;
      const float nyj = ny[j0 + j];
      u16 qs[32];
#pragma unroll
      for (int q = 0; q < 8; ++q) {
        const float4 n4 = *reinterpret_cast<const float4*>(nx + i0 + half * 64 + ig * 32 + q * 4);
        const float nn[4] = {n4.x, n4.y, n4.z, n4.w};
#pragma unroll
        for (int c = 0; c < 4; ++c) {
          const int ii = q * 4 + c;
          const float e = eb[(ig * 32 + ii) * 132 + j];
          qs[ii] = quant160(0.5f * fmaxf(nn[c] + nyj - 2.f * e, 0.f));
        }
      }
      u16* ctrow = CT + (size_t)(j0 + j) * ldct + i0 + half * 64 + ig * 32;
#pragma unroll
      for (int q = 0; q < 4; ++q) {
        uint4 v;
        v.x = (u32)qs[q * 8 + 0] | ((u32)qs[q * 8 + 1] << 16);
        v.y = (u32)qs[q * 8 + 2] | ((u32)qs[q * 8 + 3] << 16);
        v.z = (u32)qs[q * 8 + 4] | ((u32)qs[q * 8 + 5] << 16);
        v.w = (u32)qs[q * 8 + 6] | ((u32)qs[q * 8 + 7] << 16);
        *reinterpret_cast<uint4*>(ctrow + q * 8) = v;
      }
    }
    __syncthreads();
  }
}

// ---------------- online-LSE wave softmin over u16 C row (base-2 domain) ----------------
template <int NC>
__device__ __forceinline__ void softmin_online(
    const u16* __restrict__ Crow, const float* __restrict__ h,
    const float lw2, const float ie2, const float qie2, const float negeln2,
    const float* __restrict__ oldv, float* __restrict__ o,
    const int row, const bool avg, const int ln)
{
  float m = -3.0e38f, s = 0.f;
  const u16* cp = Crow + ln * 8;
  const float* hp = h + ln * 8;
  uint4 cq = *reinterpret_cast<const uint4*>(cp);
  float4 h0 = *reinterpret_cast<const float4*>(hp);
  float4 h1 = *reinterpret_cast<const float4*>(hp + 4);
#pragma unroll
  for (int k = 0; k < NC; ++k) {
    uint4 cqn; float4 h0n, h1n;
    if (k + 1 < NC) {
      cqn = *reinterpret_cast<const uint4*>(cp + (k + 1) * 512);
      h0n = *reinterpret_cast<const float4*>(hp + (k + 1) * 512);
      h1n = *reinterpret_cast<const float4*>(hp + (k + 1) * 512 + 4);
    }
    const float a0 = fmaf(h0.x, ie2, lw2) - (float)(cq.x & 0xffffu) * qie2;
    const float a1 = fmaf(h0.y, ie2, lw2) - (float)(cq.x >> 16) * qie2;
    const float a2 = fmaf(h0.z, ie2, lw2) - (float)(cq.y & 0xffffu) * qie2;
    const float a3 = fmaf(h0.w, ie2, lw2) - (float)(cq.y >> 16) * qie2;
    const float a4 = fmaf(h1.x, ie2, lw2) - (float)(cq.z & 0xffffu) * qie2;
    const float a5 = fmaf(h1.y, ie2, lw2) - (float)(cq.z >> 16) * qie2;
    const float a6 = fmaf(h1.z, ie2, lw2) - (float)(cq.w & 0xffffu) * qie2;
    const float a7 = fmaf(h1.w, ie2, lw2) - (float)(cq.w >> 16) * qie2;
    const float cm = fmaxf(fmaxf(fmaxf(a0, a1), fmaxf(a2, a3)),
                           fmaxf(fmaxf(a4, a5), fmaxf(a6, a7)));
    const float nm = fmaxf(m, cm);
    float e = fexp2(a0 - nm);
    e += fexp2(a1 - nm);
    e += fexp2(a2 - nm);
    e += fexp2(a3 - nm);
    e += fexp2(a4 - nm);
    e += fexp2(a5 - nm);
    e += fexp2(a6 - nm);
    e += fexp2(a7 - nm);
    s = fmaf(s, fexp2(m - nm), e);
    m = nm;
    cq = cqn; h0 = h0n; h1 = h1n;
  }
#pragma unroll
  for (int off = 32; off; off >>= 1) {
    const float om = __shfl_xor(m, off);
    const float os = __shfl_xor(s, off);
    const float nm = fmaxf(m, om);
    s = fmaf(s, fexp2(m - nm), os * fexp2(om - nm));
    m = nm;
  }
  if (ln == 0) {
    float v = negeln2 * (m + flog2(s));
    if (avg) v = 0.5f * (oldv[row] + v);
    o[row] = v;
  }
}

// one launch = one Sinkhorn iteration for BOTH divergences (16384 wave-tasks)
__global__ __launch_bounds__(256, 4) void sinkhorn_iter_kernel(
    float* __restrict__ ws, const float ie2, const float negeln2, const float qie2,
    const int cur, const int fin)
{
  const int wv = threadIdx.x >> 6, ln = threadIdx.x & 63;
  const int task = blockIdx.x * 4 + wv;
  const int dv = task >> 13;
  const int r = task & 8191;
  float* pot  = ws + OFF_POT + dv * 16384;
  float* outv = ws + OFF_OUT + dv * 8192;
  const u16* cq = reinterpret_cast<const u16*>(ws + OFF_CQ) + (size_t)dv * CQ_DV;
  float* fc = pot + cur * 4096;
  float* fn = pot + (cur ^ 1) * 4096;
  float* gc = pot + 8192 + cur * 2048;
  float* gn = pot + 8192 + (cur ^ 1) * 2048;
  float* yc = pot + 12288 + cur * 2048;
  float* yn = pot + 12288 + (cur ^ 1) * 2048;
  if (r < 4096) {          // ft: rows of Cxy, h = g
    softmin_online<4>(cq + (size_t)r * 2048, gc, LOGB * LOG2E, ie2, qie2, negeln2,
                      fc, fin ? outv : fn, r, !fin, ln);
  } else if (r < 6144) {   // gy: rows of Cyy, h = gy
    const int rr = r - 4096;
    softmin_online<4>(cq + CQ_YY + (size_t)rr * 2048, yc, LOGB * LOG2E, ie2, qie2, negeln2,
                      yc, fin ? (outv + 6144) : yn, rr, !fin, ln);
  } else {                 // gt: rows of Cyx, h = f
    const int rr = r - 6144;
    softmin_online<8>(cq + CQ_YX + (size_t)rr * 4096, fc, LOGA * LOG2E, ie2, qie2, negeln2,
                      gc, fin ? (outv + 4096) : gn, rr, !fin, ln);
  }
}

__global__ void init_pot_kernel(float* __restrict__ ws)
{
  const int i = blockIdx.x * 256 + threadIdx.x;
  if (i < 32768) ws[OFF_POT + i] = 0.f;
}

__global__ __launch_bounds__(256) void finalize_kernel(
    const float* __restrict__ ws, float* __restrict__ out)
{
  const float* ov = ws + OFF_OUT;
  const int tid = threadIdx.x;
  float v[6] = {0.f, 0.f, 0.f, 0.f, 0.f, 0.f};
  for (int i = tid; i < 4096; i += 256) { v[0] += ov[i]; v[3] += ov[8192 + i]; }
  for (int i = tid; i < 2048; i += 256) {
    v[1] += ov[4096 + i]; v[2] += ov[6144 + i];
    v[4] += ov[8192 + 4096 + i]; v[5] += ov[8192 + 6144 + i];
  }
  __shared__ float sh[6][4];
  const int wv = tid >> 6, ln = tid & 63;
#pragma unroll
  for (int q = 0; q < 6; ++q) {
    float s = v[q];
#pragma unroll
    for (int off = 32; off; off >>= 1) s += __shfl_xor(s, off);
    if (ln == 0) sh[q][wv] = s;
  }
  __syncthreads();
  if (tid == 0) {
    float t[6];
#pragma unroll
    for (int q = 0; q < 6; ++q) t[q] = sh[q][0] + sh[q][1] + sh[q][2] + sh[q][3];
    const float d1 = t[0] * (1.f / 4096.f) + (t[1] - t[2]) * (1.f / 2048.f);
    const float d2 = t[3] * (1.f / 4096.f) + (t[4] - t[5]) * (1.f / 2048.f);
    const float z = 0.1f * (d2 - d1);
    out[0] = 1.f / (1.f + expf(-z));
  }
}

extern "C" void kernel_launch(void* const* d_in, const int* in_sizes, int n_in,
                              void* d_out, int out_size, void* d_ws, size_t ws_size,
                              hipStream_t stream)
{
  const float* d  = (const float*)d_in[0];   // [4096][768]
  const float* s1 = (const float*)d_in[1];   // [2048][768]
  const float* s2 = (const float*)d_in[2];   // [2048][768]
  const float* Mw = (const float*)d_in[3];   // [768][128]
  float* out = (float*)d_out;
  float* ws = (float*)d_ws;

  float eps_l[NE];
  {
    double e = 1024.0;
    const double sc = 0.8 * 0.8;
    for (int k = 0; k < NE - 1; ++k) { eps_l[k] = (float)e; e *= sc; }
    eps_l[NE - 1] = (float)(0.05 * 0.05);
  }

  u16* thi = (u16*)ws;
  u16* tlo = thi + 1048576;
  const float* nd = ws + OFF_N;
  u16* cq0 = (u16*)(ws + OFF_CQ);

  prep_m_kernel<<<48, 256, 0, stream>>>(Mw, ws);
  transform_kernel<<<64, 256, 0, stream>>>(d, s1, s2, ws);

  for (int dv = 0; dv < 2; ++dv) {
    const u16* yhi = thi + (size_t)(4096 + dv * 2048) * 128;
    const u16* ylo = tlo + (size_t)(4096 + dv * 2048) * 128;
    const float* nv = nd + 4096 + dv * 2048;
    u16* cxy = cq0 + (size_t)dv * CQ_DV;
    u16* cyx = cxy + CQ_YX;
    u16* cyy = cxy + CQ_YY;
    dim3 gA(32, 16), gB(16, 16);
    cost_kernel<<<gA, 256, 0, stream>>>(thi, tlo, yhi, ylo, nd, nv, cxy, cyx, 2048, 4096);
    cost_kernel<<<gB, 256, 0, stream>>>(yhi, ylo, yhi, ylo, nv, nv, cyy, nullptr, 2048, 0);
  }

  init_pot_kernel<<<128, 256, 0, stream>>>(ws);
  int cur = 0;
  for (int it = 0; it <= NE; ++it) {
    const int fin = (it == NE);
    const float e = eps_l[fin ? NE - 1 : it];
    const float ie2 = LOG2E / e;
    const float qie2 = (QMAX / 65535.0f) * ie2;
    sinkhorn_iter_kernel<<<4096, 256, 0, stream>>>(ws, ie2, -e * LN2, qie2, cur, fin);
    if (!fin) cur ^= 1;
  }

  finalize_kernel<<<1, 256, 0, stream>>>(ws, out);
  (void)in_sizes; (void)n_in; (void)out_size; (void)ws_size;
}